// Round 7
// baseline (41.124 us; speedup 1.0000x reference)
//
#include <hip/hip_runtime.h>
#include <math.h>

#define BATCH 8
#define LEN   2048
#define FEAT  8
#define IR    4                     // pred rows register-tiled per lane
#define WAVES 4
#define THREADS (WAVES * 64)        // 256
#define ROWS  (WAVES * IR)          // 16 pred rows per block
#define CHUNK 1024                  // target rows staged per phase (36 KB LDS)
#define KSTEPS (CHUNK / 64)         // 16 j-iterations per lane per phase
#define NBLK  (BATCH * (LEN / ROWS))  // 1024 blocks = 4/CU
#define LOG2E 1.4426950408889634f
#define LN2   0.6931471805599453f
#define FIXSCALE 4294967296.0       // 2^32 fixed-point scale for det. sum

typedef float v2f __attribute__((ext_vector_type(2)));

__device__ __forceinline__ v2f pk_mul(v2f a, v2f b) {
    v2f d; asm("v_pk_mul_f32 %0, %1, %2" : "=v"(d) : "v"(a), "v"(b)); return d;
}
__device__ __forceinline__ v2f pk_fma(v2f a, v2f b, v2f c) {
    v2f d; asm("v_pk_fma_f32 %0, %1, %2, %3" : "=v"(d) : "v"(a), "v"(b), "v"(c)); return d;
}
__device__ __forceinline__ float exp2_hw(float x) {
    float d; asm("v_exp_f32 %0, %1" : "=v"(d) : "v"(x)); return d;
}
__device__ __forceinline__ float log2_hw(float x) {
    float d; asm("v_log_f32 %0, %1" : "=v"(d) : "v"(x)); return d;
}

// ws layout: [0..3] u32 finished-block counter, [8..15] u64 fixed-point sum.
__global__ void zero_ws(ulonglong2* p) {
    if (threadIdx.x == 0) p[0] = (ulonglong2){0ull, 0ull};
}

// Single fused kernel. Hot loop identical to round 6 (two 1024-row LDS
// phases, swizzled conflict-free b128, pk-packed dot, hw exp2).
// Tail protocol (round-7 change): RELAXED agent-scope atomics only --
// no ACQ_REL, hence no per-block buffer_inv/buffer_wbl2 L2 maintenance
// (suspected +12us storm in rounds 5/6). Determinism: per-block partial is
// converted to 2^32 fixed-point int64 and atomicAdd'ed (integer adds
// commute -> bitwise-identical result regardless of block order).
// Visibility: sum-add completion forced by s_waitcnt vmcnt(0) before the
// relaxed counter increment; counter==NBLK implies all sum-adds are at the
// coherent point, so the last block's relaxed atomic load sees the total.
__global__ __launch_bounds__(THREADS, 4) void dtw_fused(
    const float* __restrict__ pred, const float* __restrict__ target,
    unsigned int* __restrict__ cnt, unsigned long long* __restrict__ sum64,
    float* __restrict__ out)
{
    __shared__ float4 s_t[CHUNK * 2];   // swizzled target rows, 32 KB
    __shared__ float  s_mt2[CHUNK];     // -log2e*||t||^2, 4 KB
    __shared__ float  s_wsum[WAVES];

    const int tid = threadIdx.x;
    const int b   = blockIdx.x / (LEN / ROWS);
    const int rb  = blockIdx.x % (LEN / ROWS);
    const int w   = tid >> 6;           // wave = row-group
    const int ln  = tid & 63;           // j-lane within wave
    const int i0  = rb * ROWS + w * IR;

    // ---- this wave's 4 pred rows -> registers, pre-scaled by 2*log2e ----
    const float4* p4 = (const float4*)(pred + ((size_t)b * LEN + i0) * FEAT);
    v2f  pr[IR][4];
    float mp2[IR];
    #pragma unroll
    for (int r = 0; r < IR; ++r) {
        float4 a = p4[r * 2];
        float4 c = p4[r * 2 + 1];
        const float s2 = 2.f * LOG2E;
        pr[r][0] = (v2f){a.x * s2, a.y * s2};
        pr[r][1] = (v2f){a.z * s2, a.w * s2};
        pr[r][2] = (v2f){c.x * s2, c.y * s2};
        pr[r][3] = (v2f){c.z * s2, c.w * s2};
        mp2[r] = -LOG2E * (a.x*a.x + a.y*a.y + a.z*a.z + a.w*a.w
                         + c.x*c.x + c.y*c.y + c.z*c.z + c.w*c.w);
    }

    const float4* t4 = (const float4*)(target + (size_t)b * LEN * FEAT);
    float acc[IR];
    #pragma unroll
    for (int r = 0; r < IR; ++r) acc[r] = 0.f;

    for (int ph = 0; ph < 2; ++ph) {
        const int j0 = ph * CHUNK;
        if (ph) __syncthreads();   // prior phase's reads done before overwrite
        // ---- stage: raw target rows (swizzled) + -log2e*||t||^2 ----
        #pragma unroll
        for (int u = 0; u < CHUNK / THREADS; ++u) {
            const int jj = u * THREADS + tid;
            float4 ta = t4[(size_t)(j0 + jj) * 2];
            float4 tb = t4[(size_t)(j0 + jj) * 2 + 1];
            float t2 = ta.x*ta.x + ta.y*ta.y + ta.z*ta.z + ta.w*ta.w
                     + tb.x*tb.x + tb.y*tb.y + tb.z*tb.z + tb.w*tb.w;
            const int g = 2 * jj + ((jj >> 2) & 1);
            s_t[g]     = ta;
            s_t[g ^ 1] = tb;
            s_mt2[jj]  = -LOG2E * t2;
        }
        __syncthreads();
        // ---- compute: 16 j's per lane, 4 rows each ----
        #pragma unroll 4
        for (int k = 0; k < KSTEPS; ++k) {
            const int jj = k * 64 + ln;
            const int g  = 2 * jj + ((jj >> 2) & 1);
            float4 ta = s_t[g];
            float4 tb = s_t[g ^ 1];
            float mt2 = s_mt2[jj];
            v2f t01 = (v2f){ta.x, ta.y};
            v2f t23 = (v2f){ta.z, ta.w};
            v2f t45 = (v2f){tb.x, tb.y};
            v2f t67 = (v2f){tb.z, tb.w};
            #pragma unroll
            for (int r = 0; r < IR; ++r) {
                v2f a2 = pk_mul(t01, pr[r][0]);
                a2 = pk_fma(t23, pr[r][1], a2);
                a2 = pk_fma(t45, pr[r][2], a2);
                a2 = pk_fma(t67, pr[r][3], a2);
                float x = (a2.x + a2.y) + (mp2[r] + mt2);
                acc[r] += exp2_hw(x);          // = exp(-dist)
            }
        }
    }

    // ---- per-row totals across the wave's 64 j-lanes, then soft-min ----
    float vt = 0.f;
    #pragma unroll
    for (int r = 0; r < IR; ++r) {
        float s = acc[r];
        s += __shfl_xor(s, 1);
        s += __shfl_xor(s, 2);
        s += __shfl_xor(s, 4);
        s += __shfl_xor(s, 8);
        s += __shfl_xor(s, 16);
        s += __shfl_xor(s, 32);
        vt += log2_hw(s);                // log2(sum exp(-d))
    }
    vt *= -LN2;                          // sum over this wave's 4 rows
    if (ln == 0) s_wsum[w] = vt;
    __syncthreads();

    // ---- deterministic relaxed-atomic tail (one thread per block) ----
    if (tid == 0) {
        float tot = s_wsum[0] + s_wsum[1] + s_wsum[2] + s_wsum[3];
        long long fx = (long long)((double)tot * FIXSCALE);
        atomicAdd(sum64, (unsigned long long)fx);            // relaxed, agent
        asm volatile("s_waitcnt vmcnt(0)" ::: "memory");     // sum at coherent pt
        unsigned old = __hip_atomic_fetch_add(
            cnt, 1u, __ATOMIC_RELAXED, __HIP_MEMORY_SCOPE_AGENT);
        if (old == NBLK - 1) {
            unsigned long long s64 = __hip_atomic_load(
                sum64, __ATOMIC_RELAXED, __HIP_MEMORY_SCOPE_AGENT);
            double val = (double)(long long)s64 * (1.0 / FIXSCALE);
            out[0] = (float)(val * (1.0 / (BATCH * LEN)));
        }
    }
}

extern "C" void kernel_launch(void* const* d_in, const int* in_sizes, int n_in,
                              void* d_out, int out_size, void* d_ws, size_t ws_size,
                              hipStream_t stream) {
    const float* pred   = (const float*)d_in[0];
    const float* target = (const float*)d_in[1];
    float* out = (float*)d_out;
    unsigned int*       cnt   = (unsigned int*)d_ws;
    unsigned long long* sum64 = (unsigned long long*)((char*)d_ws + 8);

    zero_ws<<<1, 64, 0, stream>>>((ulonglong2*)d_ws);
    dtw_fused<<<NBLK, THREADS, 0, stream>>>(pred, target, cnt, sum64, out);
}

// Round 9
// 25.725 us; speedup vs baseline: 1.5986x; 1.5986x over previous
//
#include <hip/hip_runtime.h>
#include <math.h>

#define BATCH 8
#define LEN   2048
#define FEAT  8
#define IR    4                     // pred rows register-tiled per lane
#define WAVES 4
#define THREADS (WAVES * 64)        // 256
#define ROWS  (WAVES * IR)          // 16 pred rows per block
#define CHUNK 1024                  // target rows staged per phase (20 KB LDS)
#define KSTEPS (CHUNK / 64)         // 16 j-iterations per lane per phase
#define NBLK  (BATCH * (LEN / ROWS))  // 1024 blocks = 4/CU
#define LOG2E 1.4426950408889634f
#define LN2   0.6931471805599453f

typedef float    v2f __attribute__((ext_vector_type(2)));
typedef _Float16 h2  __attribute__((ext_vector_type(2)));

struct alignas(16) Row16 { h2 q[4]; };   // one target row: 8 x fp16 = 16 B

__device__ __forceinline__ v2f pk_mul(v2f a, v2f b) {
    v2f d; asm("v_pk_mul_f32 %0, %1, %2" : "=v"(d) : "v"(a), "v"(b)); return d;
}
__device__ __forceinline__ v2f pk_fma(v2f a, v2f b, v2f c) {
    v2f d; asm("v_pk_fma_f32 %0, %1, %2, %3" : "=v"(d) : "v"(a), "v"(b), "v"(c)); return d;
}
__device__ __forceinline__ float exp2_hw(float x) {
    float d; asm("v_exp_f32 %0, %1" : "=v"(d) : "v"(x)); return d;
}
__device__ __forceinline__ float log2_hw(float x) {
    float d; asm("v_log_f32 %0, %1" : "=v"(d) : "v"(x)); return d;
}

// Round-9: fp16 STORAGE (one ds_read_b128 per j-step, the round-8 goal) but
// ALL ARITHMETIC IN F32 via the round-4-proven pk_mul/pk_fma chain -- the
// round-8 failure (absmax 0.358, ~35000x too large for rounding noise) is by
// elimination attributed to the unverifiable __builtin_amdgcn_fdot2 path,
// now removed. Consistency hardening: mp2/mt2 are computed from the SAME
// fp16-rounded values used in the cross term, so
//   d~ = ||p~||^2 + ||t~||^2 - 2 p~.t~ = ||p~ - t~||^2 >= 0,
// with error vs true d of ~2(p-t).(eps) -- negligible for the near pairs
// that dominate the soft-min (threshold 1.03e-2, expected err ~1e-3).
//   pr = (2*log2e)*f32(p~), mp2 = -log2e*||f32(p~)||^2,
//   s_mt2 = -log2e*||f32(t~)||^2;  x = pr.t~ + mp2 + mt2 = -log2e*d~;
//   exp2(x) = exp(-d~).
// Two-kernel structure (rounds 5-7 proved fused atomic tails cost +13-18us).
template <bool ATOMIC>
__global__ __launch_bounds__(THREADS, 4) void dtw_rows(
    const float* __restrict__ pred, const float* __restrict__ target,
    float* __restrict__ partial_or_out)
{
    __shared__ Row16 s_t[CHUNK];        // fp16 target rows, 16 KB
    __shared__ float s_mt2[CHUNK];      // -log2e*||t~||^2 (fp32), 4 KB
    __shared__ float s_wsum[WAVES];

    const int tid = threadIdx.x;
    const int b   = blockIdx.x / (LEN / ROWS);
    const int rb  = blockIdx.x % (LEN / ROWS);
    const int w   = tid >> 6;           // wave = row-group
    const int ln  = tid & 63;           // j-lane within wave
    const int i0  = rb * ROWS + w * IR;

    // ---- this wave's 4 pred rows: round to fp16, back to f32, fold scale ----
    const float4* p4 = (const float4*)(pred + ((size_t)b * LEN + i0) * FEAT);
    v2f  pr[IR][4];
    float mp2[IR];
    #pragma unroll
    for (int r = 0; r < IR; ++r) {
        float4 a = p4[r * 2];
        float4 c = p4[r * 2 + 1];
        float f0 = (float)(_Float16)a.x, f1 = (float)(_Float16)a.y;
        float f2 = (float)(_Float16)a.z, f3 = (float)(_Float16)a.w;
        float f4 = (float)(_Float16)c.x, f5 = (float)(_Float16)c.y;
        float f6 = (float)(_Float16)c.z, f7 = (float)(_Float16)c.w;
        const float s2 = 2.f * LOG2E;
        pr[r][0] = (v2f){f0 * s2, f1 * s2};
        pr[r][1] = (v2f){f2 * s2, f3 * s2};
        pr[r][2] = (v2f){f4 * s2, f5 * s2};
        pr[r][3] = (v2f){f6 * s2, f7 * s2};
        mp2[r] = -LOG2E * (f0*f0 + f1*f1 + f2*f2 + f3*f3
                         + f4*f4 + f5*f5 + f6*f6 + f7*f7);
    }

    const float4* t4 = (const float4*)(target + (size_t)b * LEN * FEAT);
    float acc[IR];
    #pragma unroll
    for (int r = 0; r < IR; ++r) acc[r] = 0.f;

    for (int ph = 0; ph < 2; ++ph) {
        const int j0 = ph * CHUNK;
        if (ph) __syncthreads();  // prior phase's reads done before overwrite
        // ---- stage: f32 load -> fp16 row; mt2 from the ROUNDED values ----
        #pragma unroll
        for (int u = 0; u < CHUNK / THREADS; ++u) {
            const int jj = u * THREADS + tid;
            float4 ta = t4[(size_t)(j0 + jj) * 2];
            float4 tb = t4[(size_t)(j0 + jj) * 2 + 1];
            Row16 rw;
            rw.q[0] = (h2){(_Float16)ta.x, (_Float16)ta.y};
            rw.q[1] = (h2){(_Float16)ta.z, (_Float16)ta.w};
            rw.q[2] = (h2){(_Float16)tb.x, (_Float16)tb.y};
            rw.q[3] = (h2){(_Float16)tb.z, (_Float16)tb.w};
            float u0 = (float)rw.q[0].x, u1 = (float)rw.q[0].y;
            float u2 = (float)rw.q[1].x, u3 = (float)rw.q[1].y;
            float u4 = (float)rw.q[2].x, u5 = (float)rw.q[2].y;
            float u6 = (float)rw.q[3].x, u7 = (float)rw.q[3].y;
            float t2 = u0*u0 + u1*u1 + u2*u2 + u3*u3
                     + u4*u4 + u5*u5 + u6*u6 + u7*u7;
            s_t[jj]   = rw;
            s_mt2[jj] = -LOG2E * t2;
        }
        __syncthreads();
        // ---- compute: 16 j's per lane, 4 rows each ----
        #pragma unroll 4
        for (int k = 0; k < KSTEPS; ++k) {
            const int jj = k * 64 + ln;
            Row16 t = s_t[jj];               // one ds_read_b128
            float mt2 = s_mt2[jj];
            v2f T0 = (v2f){(float)t.q[0].x, (float)t.q[0].y};
            v2f T1 = (v2f){(float)t.q[1].x, (float)t.q[1].y};
            v2f T2 = (v2f){(float)t.q[2].x, (float)t.q[2].y};
            v2f T3 = (v2f){(float)t.q[3].x, (float)t.q[3].y};
            #pragma unroll
            for (int r = 0; r < IR; ++r) {
                v2f a2 = pk_mul(T0, pr[r][0]);
                a2 = pk_fma(T1, pr[r][1], a2);
                a2 = pk_fma(T2, pr[r][2], a2);
                a2 = pk_fma(T3, pr[r][3], a2);
                float x = (a2.x + a2.y) + (mp2[r] + mt2);  // -log2e * d~
                acc[r] += exp2_hw(x);                      // = exp(-d~)
            }
        }
    }

    // ---- per-row totals across the wave's 64 j-lanes, then soft-min ----
    float vt = 0.f;
    #pragma unroll
    for (int r = 0; r < IR; ++r) {
        float s = acc[r];
        s += __shfl_xor(s, 1);
        s += __shfl_xor(s, 2);
        s += __shfl_xor(s, 4);
        s += __shfl_xor(s, 8);
        s += __shfl_xor(s, 16);
        s += __shfl_xor(s, 32);
        vt += log2_hw(s);                // log2(sum exp(-d))
    }
    vt *= -LN2;                          // sum over this wave's 4 rows
    if (ln == 0) s_wsum[w] = vt;
    __syncthreads();
    if (tid == 0) {
        float tot = s_wsum[0] + s_wsum[1] + s_wsum[2] + s_wsum[3];
        if (ATOMIC) {
            atomicAdd(partial_or_out, tot * (1.0f / (BATCH * LEN)));
        } else {
            partial_or_out[blockIdx.x] = tot;
        }
    }
}

__global__ __launch_bounds__(256) void dtw_reduce(
    const float* __restrict__ partial, float* __restrict__ out)
{
    __shared__ float s_w[4];
    const int tid = threadIdx.x;
    float v = partial[tid] + partial[tid + 256]
            + partial[tid + 512] + partial[tid + 768];   // NBLK = 1024
    v += __shfl_xor(v, 1);
    v += __shfl_xor(v, 2);
    v += __shfl_xor(v, 4);
    v += __shfl_xor(v, 8);
    v += __shfl_xor(v, 16);
    v += __shfl_xor(v, 32);
    if ((tid & 63) == 0) s_w[tid >> 6] = v;
    __syncthreads();
    if (tid == 0)
        out[0] = (s_w[0] + s_w[1] + s_w[2] + s_w[3]) * (1.0f / (BATCH * LEN));
}

extern "C" void kernel_launch(void* const* d_in, const int* in_sizes, int n_in,
                              void* d_out, int out_size, void* d_ws, size_t ws_size,
                              hipStream_t stream) {
    const float* pred   = (const float*)d_in[0];
    const float* target = (const float*)d_in[1];
    float* out = (float*)d_out;

    if (ws_size >= NBLK * sizeof(float)) {
        float* partial = (float*)d_ws;
        dtw_rows<false><<<NBLK, THREADS, 0, stream>>>(pred, target, partial);
        dtw_reduce<<<1, 256, 0, stream>>>(partial, out);
    } else {
        hipMemsetAsync(d_out, 0, sizeof(float), stream);
        dtw_rows<true><<<NBLK, THREADS, 0, stream>>>(pred, target, out);
    }
}

// Round 10
// 16.870 us; speedup vs baseline: 2.4376x; 1.5249x over previous
//
#include <hip/hip_runtime.h>
#include <math.h>

#define BATCH 8
#define LEN   2048
#define FEAT  8
#define MROWS 16                      // pred rows per block = MFMA M
#define WAVES 4
#define THREADS 256
#define JW    (LEN / WAVES)           // 512 targets per wave (j-split)
#define NCHUNK (JW / 16)              // 32 MFMAs per wave
#define NBLK  (BATCH * (LEN / MROWS)) // 1024 blocks = 4/CU
#define LOG2E 1.4426950408889634f
#define LN2   0.6931471805599453f

typedef _Float16 f16x8 __attribute__((ext_vector_type(8)));
typedef float    f32x4 __attribute__((ext_vector_type(4)));

__device__ __forceinline__ float exp2_hw(float x) {
    float d; asm("v_exp_f32 %0, %1" : "=v"(d) : "v"(x)); return d;
}
__device__ __forceinline__ float log2_hw(float x) {
    float d; asm("v_log_f32 %0, %1" : "=v"(d) : "v"(x)); return d;
}

// Round-10: the cross term is a K=8 GEMM -> MFMA. Per block: one 16-row pred
// stripe (M=16), all 2048 targets of the batch staged once in LDS as fp16
// rows (32KB) + f32 -log2e*||t~||^2 (8KB) = exactly 40KB -> 4 blocks/CU.
// j-split: wave w sweeps targets [w*512,(w+1)*512) -> each t-row LDS-read
// once per block. Math (consistent-rounding, R9-proven class):
//   A = 2*p~ (fp16, exact scale), B = t~ (fp16); S = mfma(A,B) = 2 p~.t~
//   (f32-exact products); x = fma(S, log2e, -log2e*(p2+t2)) = -log2e*d~;
//   exp2(x) = exp(-d~), d~ = ||p~-t~||^2 >= 0.
// Layouts: C/D col=lane&15, row=(lane>>4)*4+reg [HW-verified, guide m89/91];
// A row=lane&15 k=(lane>>4)*8+e, B col=lane&15 same k-grouping -- symmetric,
// so any consistent k-permutation cancels in the dot. K=8 real, lanes>=16
// hold zeros. Per-pair epilogue: 1 fma + 1 exp2 + 1 add (vs ~20 scalar ops
// in rounds 2-9 -- the measured VALU-issue bottleneck).
// mp2 distributed by shuffles from lanes 0-15 (no LDS slot -> stays 40960B).
// s_red aliased into s_t16 (barrier-separated). Two-kernel structure
// (rounds 5-7: fused atomic tails cost +13..18us).
template <bool ATOMIC>
__global__ __launch_bounds__(THREADS, 4) void dtw_mfma(
    const float* __restrict__ pred, const float* __restrict__ target,
    float* __restrict__ partial_or_out)
{
    __shared__ f16x8 s_t16[LEN];   // 32 KB fp16 target rows
    __shared__ float s_mt2[LEN];   // 8 KB  -log2e*||t~||^2

    const int tid = threadIdx.x;
    const int b   = blockIdx.x / (LEN / MROWS);
    const int rs  = blockIdx.x % (LEN / MROWS);
    const int w   = tid >> 6;
    const int ln  = tid & 63;
    const int i0  = rs * MROWS;

    // ---- stage all 2048 target rows of batch b ----
    const float4* t4 = (const float4*)(target + (size_t)b * LEN * FEAT);
    for (int jj = tid; jj < LEN; jj += THREADS) {
        float4 ta = t4[(size_t)jj * 2];
        float4 tb = t4[(size_t)jj * 2 + 1];
        f16x8 h;
        h[0] = (_Float16)ta.x; h[1] = (_Float16)ta.y;
        h[2] = (_Float16)ta.z; h[3] = (_Float16)ta.w;
        h[4] = (_Float16)tb.x; h[5] = (_Float16)tb.y;
        h[6] = (_Float16)tb.z; h[7] = (_Float16)tb.w;
        float t2 = 0.f;
        #pragma unroll
        for (int e = 0; e < 8; ++e) { float f = (float)h[e]; t2 += f * f; }
        s_t16[jj]  = h;
        s_mt2[jj]  = -LOG2E * t2;
    }

    // ---- A-frag: lanes 0-15 hold pred row (i0+ln), k=0..7; rest zero ----
    f16x8 afrag;
    #pragma unroll
    for (int e = 0; e < 8; ++e) afrag[e] = (_Float16)0.f;
    float mp2_lane = 0.f;
    if (ln < 16) {
        const float4* p4 =
            (const float4*)(pred + ((size_t)b * LEN + i0 + ln) * FEAT);
        float4 a = p4[0], c = p4[1];
        f16x8 h;
        h[0] = (_Float16)a.x; h[1] = (_Float16)a.y;
        h[2] = (_Float16)a.z; h[3] = (_Float16)a.w;
        h[4] = (_Float16)c.x; h[5] = (_Float16)c.y;
        h[6] = (_Float16)c.z; h[7] = (_Float16)c.w;
        float p2 = 0.f;
        #pragma unroll
        for (int e = 0; e < 8; ++e) { float f = (float)h[e]; p2 += f * f; }
        #pragma unroll
        for (int e = 0; e < 8; ++e) afrag[e] = h[e] * (_Float16)2.0f; // exact
        mp2_lane = -LOG2E * p2;
    }
    // mp2 for this lane's 4 C-rows ((ln>>4)*4 + r), sourced from lanes 0-15
    float m2r[4];
    #pragma unroll
    for (int r = 0; r < 4; ++r)
        m2r[r] = __shfl(mp2_lane, (ln >> 4) * 4 + r);

    __syncthreads();   // staging visible

    // ---- j-loop: 32 MFMAs over this wave's 512 targets ----
    const int jbase = w * JW;
    f32x4 acc = {0.f, 0.f, 0.f, 0.f};
    #pragma unroll 4
    for (int ch = 0; ch < NCHUNK; ++ch) {
        const int j0 = jbase + ch * 16;
        f16x8 bfrag;
        #pragma unroll
        for (int e = 0; e < 8; ++e) bfrag[e] = (_Float16)0.f;
        if (ln < 16) bfrag = s_t16[j0 + ln];          // one b128, 16 lanes
        float mt2c = s_mt2[j0 + (ln & 15)];           // bcast read
        f32x4 S = __builtin_amdgcn_mfma_f32_16x16x32_f16(
            afrag, bfrag, (f32x4){0.f, 0.f, 0.f, 0.f}, 0, 0, 0);
        #pragma unroll
        for (int r = 0; r < 4; ++r) {
            float x = fmaf(S[r], LOG2E, m2r[r] + mt2c);   // = -log2e * d~
            acc[r] += exp2_hw(x);                         // = exp(-d~)
        }
    }

    // ---- sum each row across its 16-lane col group ----
    #pragma unroll
    for (int m = 1; m < 16; m <<= 1) {
        #pragma unroll
        for (int r = 0; r < 4; ++r) acc[r] += __shfl_xor(acc[r], m);
    }

    // ---- cross-wave row sums via LDS (aliased into s_t16, barrier-safe) ----
    __syncthreads();                      // all waves done reading s_t16
    float* s_red = (float*)s_t16;         // [wave][16] row partials
    if ((ln & 15) == 0) {
        #pragma unroll
        for (int r = 0; r < 4; ++r)
            s_red[w * 16 + (ln >> 4) * 4 + r] = acc[r];
    }
    __syncthreads();
    if (tid < 16) {
        float s = s_red[tid] + s_red[16 + tid] + s_red[32 + tid]
                + s_red[48 + tid];
        float v = log2_hw(s);             // log2(sum exp(-d)) for row tid
        v += __shfl_xor(v, 1);
        v += __shfl_xor(v, 2);
        v += __shfl_xor(v, 4);
        v += __shfl_xor(v, 8);
        if (tid == 0) {
            float tot = -LN2 * v;         // -gamma * ln-sum over 16 rows
            if (ATOMIC) {
                atomicAdd(partial_or_out, tot * (1.0f / (BATCH * LEN)));
            } else {
                partial_or_out[blockIdx.x] = tot;
            }
        }
    }
}

__global__ __launch_bounds__(256) void dtw_reduce(
    const float* __restrict__ partial, float* __restrict__ out)
{
    __shared__ float s_w[4];
    const int tid = threadIdx.x;
    float v = partial[tid] + partial[tid + 256]
            + partial[tid + 512] + partial[tid + 768];   // NBLK = 1024
    v += __shfl_xor(v, 1);
    v += __shfl_xor(v, 2);
    v += __shfl_xor(v, 4);
    v += __shfl_xor(v, 8);
    v += __shfl_xor(v, 16);
    v += __shfl_xor(v, 32);
    if ((tid & 63) == 0) s_w[tid >> 6] = v;
    __syncthreads();
    if (tid == 0)
        out[0] = (s_w[0] + s_w[1] + s_w[2] + s_w[3]) * (1.0f / (BATCH * LEN));
}

extern "C" void kernel_launch(void* const* d_in, const int* in_sizes, int n_in,
                              void* d_out, int out_size, void* d_ws, size_t ws_size,
                              hipStream_t stream) {
    const float* pred   = (const float*)d_in[0];
    const float* target = (const float*)d_in[1];
    float* out = (float*)d_out;

    if (ws_size >= NBLK * sizeof(float)) {
        float* partial = (float*)d_ws;
        dtw_mfma<false><<<NBLK, THREADS, 0, stream>>>(pred, target, partial);
        dtw_reduce<<<1, 256, 0, stream>>>(partial, out);
    } else {
        hipMemsetAsync(d_out, 0, sizeof(float), stream);
        dtw_mfma<true><<<NBLK, THREADS, 0, stream>>>(pred, target, out);
    }
}

// Round 11
// 16.036 us; speedup vs baseline: 2.5644x; 1.0520x over previous
//
#include <hip/hip_runtime.h>
#include <math.h>

#define BATCH 8
#define LEN   2048
#define FEAT  8
#define MROWS 64                      // pred rows per block (4 x 16-row groups)
#define THREADS 1024                  // 16 waves: rg = w>>2, jq = w&3
#define JW    (LEN / 4)               // 512 targets per j-quarter
#define NCHUNK (JW / 16)              // 32 MFMAs per wave
#define NBLK  (BATCH * (LEN / MROWS)) // 256 blocks = 1/CU
#define LOG2E 1.4426950408889634f
#define LN2   0.6931471805599453f

typedef _Float16 f16x8 __attribute__((ext_vector_type(8)));
typedef float    f32x4 __attribute__((ext_vector_type(4)));

__device__ __forceinline__ float exp2_hw(float x) {
    float d; asm("v_exp_f32 %0, %1" : "=v"(d) : "v"(x)); return d;
}
__device__ __forceinline__ float log2_hw(float x) {
    float d; asm("v_log_f32 %0, %1" : "=v"(d) : "v"(x)); return d;
}

// Round-11: amortize staging. Round-10 (M=16, 1024 blocks) re-staged all 2048
// target rows per block -> staging ~ j-loop cost, done 128x per batch. Now
// M=64 per block, 16 waves = 4 row-groups x 4 j-quarters, 256 blocks = 1/CU:
// staging work and global target traffic / 4, j-loop work per pair unchanged
// (each wave: one 16-row A-frag, 32 MFMAs over its 512-target quarter; each
// t-row LDS-read by 4 waves).
// Math identical to round-10 (proven): A = 2*p~ fp16 (exact scale), B = t~;
// S = 2 p~.t~ f32-exact; x = fma(S, log2e, -log2e*(p2~+t2~)) = -log2e*d~,
// d~ = ||p~-t~||^2 >= 0; exp2(x) = exp(-d~). C/D: col=lane&15,
// row=(lane>>4)*4+reg [HW-verified]. A/B k-grouping symmetric -> cancels.
// LDS 40960 B (s_red aliased into s_t16, barrier-separated).
// Two-kernel structure (rounds 5-7: fused atomic tails cost +13..18us).
template <bool ATOMIC>
__global__ __launch_bounds__(THREADS, 4) void dtw_mfma(
    const float* __restrict__ pred, const float* __restrict__ target,
    float* __restrict__ partial_or_out)
{
    __shared__ f16x8 s_t16[LEN];   // 32 KB fp16 target rows
    __shared__ float s_mt2[LEN];   // 8 KB  -log2e*||t~||^2

    const int tid = threadIdx.x;
    const int b   = blockIdx.x / (LEN / MROWS);
    const int rs  = blockIdx.x % (LEN / MROWS);
    const int w   = tid >> 6;
    const int rg  = w >> 2;            // row-group 0..3
    const int jq  = w & 3;             // j-quarter 0..3
    const int ln  = tid & 63;
    const int i0  = rs * MROWS + rg * 16;

    // ---- stage all 2048 target rows of batch b (2 rows per thread) ----
    const float4* t4 = (const float4*)(target + (size_t)b * LEN * FEAT);
    #pragma unroll
    for (int u = 0; u < LEN / THREADS; ++u) {
        const int jj = u * THREADS + tid;
        float4 ta = t4[(size_t)jj * 2];
        float4 tb = t4[(size_t)jj * 2 + 1];
        f16x8 h;
        h[0] = (_Float16)ta.x; h[1] = (_Float16)ta.y;
        h[2] = (_Float16)ta.z; h[3] = (_Float16)ta.w;
        h[4] = (_Float16)tb.x; h[5] = (_Float16)tb.y;
        h[6] = (_Float16)tb.z; h[7] = (_Float16)tb.w;
        float t2 = 0.f;
        #pragma unroll
        for (int e = 0; e < 8; ++e) { float f = (float)h[e]; t2 += f * f; }
        s_t16[jj] = h;
        s_mt2[jj] = -LOG2E * t2;
    }

    // ---- A-frag: lanes 0-15 hold pred row (i0+ln), k=0..7; rest zero ----
    f16x8 afrag;
    #pragma unroll
    for (int e = 0; e < 8; ++e) afrag[e] = (_Float16)0.f;
    float mp2_lane = 0.f;
    if (ln < 16) {
        const float4* p4 =
            (const float4*)(pred + ((size_t)b * LEN + i0 + ln) * FEAT);
        float4 a = p4[0], c = p4[1];
        f16x8 h;
        h[0] = (_Float16)a.x; h[1] = (_Float16)a.y;
        h[2] = (_Float16)a.z; h[3] = (_Float16)a.w;
        h[4] = (_Float16)c.x; h[5] = (_Float16)c.y;
        h[6] = (_Float16)c.z; h[7] = (_Float16)c.w;
        float p2 = 0.f;
        #pragma unroll
        for (int e = 0; e < 8; ++e) { float f = (float)h[e]; p2 += f * f; }
        #pragma unroll
        for (int e = 0; e < 8; ++e) afrag[e] = h[e] * (_Float16)2.0f; // exact
        mp2_lane = -LOG2E * p2;
    }
    // mp2 for this lane's 4 C-rows ((ln>>4)*4 + r), sourced from lanes 0-15
    float m2r[4];
    #pragma unroll
    for (int r = 0; r < 4; ++r)
        m2r[r] = __shfl(mp2_lane, (ln >> 4) * 4 + r);

    __syncthreads();   // staging visible

    // ---- j-loop: 32 MFMAs over this wave's 512-target quarter ----
    const int jbase = jq * JW;
    f32x4 acc = {0.f, 0.f, 0.f, 0.f};
    #pragma unroll 4
    for (int ch = 0; ch < NCHUNK; ++ch) {
        const int j0 = jbase + ch * 16;
        f16x8 bfrag;
        #pragma unroll
        for (int e = 0; e < 8; ++e) bfrag[e] = (_Float16)0.f;
        if (ln < 16) bfrag = s_t16[j0 + ln];          // one b128, 16 lanes
        float mt2c = s_mt2[j0 + (ln & 15)];           // bcast read
        f32x4 S = __builtin_amdgcn_mfma_f32_16x16x32_f16(
            afrag, bfrag, (f32x4){0.f, 0.f, 0.f, 0.f}, 0, 0, 0);
        #pragma unroll
        for (int r = 0; r < 4; ++r) {
            float x = fmaf(S[r], LOG2E, m2r[r] + mt2c);   // = -log2e * d~
            acc[r] += exp2_hw(x);                         // = exp(-d~)
        }
    }

    // ---- sum each row across its 16-lane col group ----
    #pragma unroll
    for (int m = 1; m < 16; m <<= 1) {
        #pragma unroll
        for (int r = 0; r < 4; ++r) acc[r] += __shfl_xor(acc[r], m);
    }

    // ---- cross-wave row sums via LDS (aliased into s_t16, barrier-safe) ----
    __syncthreads();                      // all waves done reading s_t16
    float* s_red = (float*)s_t16;         // [row 0..63][jq 0..3] partials
    if ((ln & 15) == 0) {
        #pragma unroll
        for (int r = 0; r < 4; ++r) {
            const int row = rg * 16 + (ln >> 4) * 4 + r;
            s_red[row * 4 + jq] = acc[r];
        }
    }
    __syncthreads();
    if (tid < 64) {
        float s = s_red[tid * 4] + s_red[tid * 4 + 1]
                + s_red[tid * 4 + 2] + s_red[tid * 4 + 3];
        float v = log2_hw(s);             // log2(sum exp(-d)) for row tid
        v += __shfl_xor(v, 1);
        v += __shfl_xor(v, 2);
        v += __shfl_xor(v, 4);
        v += __shfl_xor(v, 8);
        v += __shfl_xor(v, 16);
        v += __shfl_xor(v, 32);
        if (tid == 0) {
            float tot = -LN2 * v;         // -gamma * ln-sum over 64 rows
            if (ATOMIC) {
                atomicAdd(partial_or_out, tot * (1.0f / (BATCH * LEN)));
            } else {
                partial_or_out[blockIdx.x] = tot;
            }
        }
    }
}

__global__ __launch_bounds__(256) void dtw_reduce(
    const float* __restrict__ partial, float* __restrict__ out)
{
    __shared__ float s_w[4];
    const int tid = threadIdx.x;
    float v = partial[tid];               // NBLK = 256
    v += __shfl_xor(v, 1);
    v += __shfl_xor(v, 2);
    v += __shfl_xor(v, 4);
    v += __shfl_xor(v, 8);
    v += __shfl_xor(v, 16);
    v += __shfl_xor(v, 32);
    if ((tid & 63) == 0) s_w[tid >> 6] = v;
    __syncthreads();
    if (tid == 0)
        out[0] = (s_w[0] + s_w[1] + s_w[2] + s_w[3]) * (1.0f / (BATCH * LEN));
}

extern "C" void kernel_launch(void* const* d_in, const int* in_sizes, int n_in,
                              void* d_out, int out_size, void* d_ws, size_t ws_size,
                              hipStream_t stream) {
    const float* pred   = (const float*)d_in[0];
    const float* target = (const float*)d_in[1];
    float* out = (float*)d_out;

    if (ws_size >= NBLK * sizeof(float)) {
        float* partial = (float*)d_ws;
        dtw_mfma<false><<<NBLK, THREADS, 0, stream>>>(pred, target, partial);
        dtw_reduce<<<1, 256, 0, stream>>>(partial, out);
    } else {
        hipMemsetAsync(d_out, 0, sizeof(float), stream);
        dtw_mfma<true><<<NBLK, THREADS, 0, stream>>>(pred, target, out);
    }
}

// Round 14
// 14.331 us; speedup vs baseline: 2.8695x; 1.1190x over previous
//
#include <hip/hip_runtime.h>
#include <math.h>

#define BATCH 8
#define LEN   2048
#define FEAT  8
#define MROWS 64                      // 2 row-groups x 32 rows
#define THREADS 1024                  // 16 waves: rg = w>>3, jo = w&7
#define JO    (LEN / 8)               // 256 targets per j-octant
#define NCHUNK (JO / 16)              // 16 chunks x 2 MFMAs per wave
#define NBLK  (BATCH * (LEN / MROWS)) // 256 blocks = 1/CU
#define LOG2E 1.4426950408889634f
#define LN2   0.6931471805599453f
#define P2S   (2.0f * LOG2E)          // pred pre-scale

typedef _Float16 f16x8 __attribute__((ext_vector_type(8)));
typedef float    f32x4 __attribute__((ext_vector_type(4)));

__device__ __forceinline__ float exp2_hw(float x) {
    float d; asm("v_exp_f32 %0, %1" : "=v"(d) : "v"(x)); return d;
}
__device__ __forceinline__ float log2_hw(float x) {
    float d; asm("v_log_f32 %0, %1" : "=v"(d) : "v"(x)); return d;
}

// Round-14: revert to the R11-passing MFMA usage (data ONLY in lane-group 0,
// zeros elsewhere -- the one HW-verified configuration; R12/R13 k-group
// folding produced scrambled S => overflow/NaN, abandoned). Safe deltas:
// (a) post-reduction qp: A = fp16(2*log2e*p) (group 0), B = tau (group 0);
//     S = 2*log2e*u.tau; x = S + mt2 (mt2 = -log2e*||tau||^2, b32 bcast);
//     row value = log2(sum exp2(x)) - qp = log2(sum exp(-d~)). Epilogue
//     3 VALU/pair (add, exp2, add); no per-pair fma, no m2r shuffles.
//     Range: x <= qp <= ~60 -> acc <= 2^69, f32-safe.
// (b) branchless broadcast B-read: ALL lanes read the same s_t16/s_mt2 row
//     (LDS broadcast is conflict-free); A zeros in groups 1-3 annihilate.
// (c) two A-frags per wave (rows rg*32+col, rg*32+16+col): each B-read
//     feeds 2 independent MFMAs -> j-loop LDS instrs halved, chunks halved.
// 16 waves = 2 row-groups x 8 j-octants; LDS ~42.3 KB; two-kernel structure
// (rounds 5-7: fused atomic tails cost +13..18us).
template <bool ATOMIC>
__global__ __launch_bounds__(THREADS, 4) void dtw_mfma(
    const float* __restrict__ pred, const float* __restrict__ target,
    float* __restrict__ partial_or_out)
{
    __shared__ f16x8 s_t16[LEN];        // 32 KB fp16 tau rows
    __shared__ float s_mt2[LEN];        // 8 KB  -log2e*||tau||^2
    __shared__ float s_red[MROWS * 8];  // 2 KB  per-(row, jo) partials
    __shared__ float s_qp[MROWS];       // 256 B per-row log2e*||u||^2

    const int tid = threadIdx.x;
    const int b   = blockIdx.x / (LEN / MROWS);
    const int rs  = blockIdx.x % (LEN / MROWS);
    const int w   = tid >> 6;
    const int rg  = w >> 3;            // row-group 0..1
    const int jo  = w & 7;             // j-octant 0..7
    const int ln  = tid & 63;
    const int col = ln & 15;
    const int g   = ln >> 4;           // lane-group
    const int i0  = rs * MROWS + rg * 32;

    // ---- stage all 2048 target rows of batch b (2 rows per thread) ----
    const float4* t4 = (const float4*)(target + (size_t)b * LEN * FEAT);
    #pragma unroll
    for (int u = 0; u < LEN / THREADS; ++u) {
        const int jj = u * THREADS + tid;
        float4 ta = t4[(size_t)jj * 2];
        float4 tb = t4[(size_t)jj * 2 + 1];
        f16x8 h;
        h[0] = (_Float16)ta.x; h[1] = (_Float16)ta.y;
        h[2] = (_Float16)ta.z; h[3] = (_Float16)ta.w;
        h[4] = (_Float16)tb.x; h[5] = (_Float16)tb.y;
        h[6] = (_Float16)tb.z; h[7] = (_Float16)tb.w;
        float t2 = 0.f;
        #pragma unroll
        for (int e = 0; e < 8; ++e) { float f = (float)h[e]; t2 += f * f; }
        s_t16[jj] = h;
        s_mt2[jj] = -LOG2E * t2;
    }

    // ---- two A-frags: pred rows i0+col and i0+16+col (fp16, x 2*log2e) ----
    f16x8 afrag0, afrag1;
    #pragma unroll
    for (int e = 0; e < 8; ++e) { afrag0[e] = (_Float16)0.f;
                                  afrag1[e] = (_Float16)0.f; }
    float qp0 = 0.f, qp1 = 0.f;
    {
        const float* pb = pred + ((size_t)b * LEN + i0 + col) * FEAT;
        const float4* pA = (const float4*)pb;
        const float4* pB = (const float4*)(pb + 16 * FEAT);
        float4 a0 = pA[0], c0 = pA[1], a1 = pB[0], c1 = pB[1];
        float f0[8] = {a0.x, a0.y, a0.z, a0.w, c0.x, c0.y, c0.z, c0.w};
        float f1[8] = {a1.x, a1.y, a1.z, a1.w, c1.x, c1.y, c1.z, c1.w};
        f16x8 r0, r1;
        float e0 = 0.f, e1 = 0.f;
        #pragma unroll
        for (int e = 0; e < 8; ++e) {
            r0[e] = (_Float16)(P2S * f0[e]);
            r1[e] = (_Float16)(P2S * f1[e]);
            float x0 = (float)r0[e], x1 = (float)r1[e];
            e0 += x0 * x0; e1 += x1 * x1;
        }
        qp0 = e0 * (0.25f / LOG2E);        // log2e * ||u0||^2
        qp1 = e1 * (0.25f / LOG2E);
        if (g == 0) { afrag0 = r0; afrag1 = r1; }   // data only in group 0
        if (jo == 0 && g == 0) {
            s_qp[rg * 32 + col]      = qp0;
            s_qp[rg * 32 + 16 + col] = qp1;
        }
    }

    __syncthreads();   // staging + s_qp visible

    // ---- j-loop: 16 chunks, 1 b128 + 1 b32 (broadcast) -> 2 MFMAs ----
    const int jbase = jo * JO;
    f32x4 acc0 = {0.f, 0.f, 0.f, 0.f};
    f32x4 acc1 = {0.f, 0.f, 0.f, 0.f};
    const f32x4 Z = {0.f, 0.f, 0.f, 0.f};
    #pragma unroll
    for (int ch = 0; ch < NCHUNK; ++ch) {
        const int j0 = jbase + ch * 16;
        f16x8 bfrag = s_t16[j0 + col];     // all lanes: broadcast read
        float mt2c  = s_mt2[j0 + col];
        f32x4 S0 = __builtin_amdgcn_mfma_f32_16x16x32_f16(
            afrag0, bfrag, Z, 0, 0, 0);    // S = 2*log2e*u.tau
        f32x4 S1 = __builtin_amdgcn_mfma_f32_16x16x32_f16(
            afrag1, bfrag, Z, 0, 0, 0);
        #pragma unroll
        for (int r = 0; r < 4; ++r) {
            acc0[r] += exp2_hw(S0[r] + mt2c);   // = 2^qp0 * exp(-d~)
            acc1[r] += exp2_hw(S1[r] + mt2c);
        }
    }

    // ---- sum each row across its 16-lane col group ----
    #pragma unroll
    for (int m = 1; m < 16; m <<= 1) {
        #pragma unroll
        for (int r = 0; r < 4; ++r) {
            acc0[r] += __shfl_xor(acc0[r], m);
            acc1[r] += __shfl_xor(acc1[r], m);
        }
    }
    if (col == 0) {
        #pragma unroll
        for (int r = 0; r < 4; ++r) {
            s_red[(rg * 32 + g * 4 + r) * 8 + jo]      = acc0[r];
            s_red[(rg * 32 + 16 + g * 4 + r) * 8 + jo] = acc1[r];
        }
    }
    __syncthreads();

    // ---- per-row soft-min (subtract qp exactly), block total ----
    if (tid < MROWS) {
        float s = 0.f;
        #pragma unroll
        for (int q = 0; q < 8; ++q) s += s_red[tid * 8 + q];
        float v = log2_hw(s) - s_qp[tid];   // log2(sum_j exp(-d~))
        v += __shfl_xor(v, 1);
        v += __shfl_xor(v, 2);
        v += __shfl_xor(v, 4);
        v += __shfl_xor(v, 8);
        v += __shfl_xor(v, 16);
        v += __shfl_xor(v, 32);
        if (tid == 0) {
            float tot = -LN2 * v;           // -gamma * ln-sum over 64 rows
            if (ATOMIC) {
                atomicAdd(partial_or_out, tot * (1.0f / (BATCH * LEN)));
            } else {
                partial_or_out[blockIdx.x] = tot;
            }
        }
    }
}

__global__ __launch_bounds__(256) void dtw_reduce(
    const float* __restrict__ partial, float* __restrict__ out)
{
    __shared__ float s_w[4];
    const int tid = threadIdx.x;
    float v = partial[tid];               // NBLK = 256
    v += __shfl_xor(v, 1);
    v += __shfl_xor(v, 2);
    v += __shfl_xor(v, 4);
    v += __shfl_xor(v, 8);
    v += __shfl_xor(v, 16);
    v += __shfl_xor(v, 32);
    if ((tid & 63) == 0) s_w[tid >> 6] = v;
    __syncthreads();
    if (tid == 0)
        out[0] = (s_w[0] + s_w[1] + s_w[2] + s_w[3]) * (1.0f / (BATCH * LEN));
}

extern "C" void kernel_launch(void* const* d_in, const int* in_sizes, int n_in,
                              void* d_out, int out_size, void* d_ws, size_t ws_size,
                              hipStream_t stream) {
    const float* pred   = (const float*)d_in[0];
    const float* target = (const float*)d_in[1];
    float* out = (float*)d_out;

    if (ws_size >= NBLK * sizeof(float)) {
        float* partial = (float*)d_ws;
        dtw_mfma<false><<<NBLK, THREADS, 0, stream>>>(pred, target, partial);
        dtw_reduce<<<1, 256, 0, stream>>>(partial, out);
    } else {
        hipMemsetAsync(d_out, 0, sizeof(float), stream);
        dtw_mfma<true><<<NBLK, THREADS, 0, stream>>>(pred, target, out);
    }
}